// Round 6
// baseline (1214.555 us; speedup 1.0000x reference)
//
#include <hip/hip_runtime.h>
#include <math.h>

#define B_    64
#define KP1   16385                 // K+1
#define D_    128
#define NROW  500000
#define INV_T (1.0f / 0.07f)
#define MOM_  0.5f

#define BK_    (B_ * KP1)           // 1,048,640 items per bank (divisible by 4)
#define TOT_   (2 * BK_)            // 2,097,280 score items
#define NQUAD  (TOT_ / 4)           // 524,320 quads
#define NE4B   (NROW * (D_ / 4))    // 16,000,000 float4 per bank
#define NBLK   2048
#define NTHR   (NBLK * 256)         // 524,288 threads
#define REMQ   (NQUAD - NTHR)       // 32 leftover quads
#define CP_FULL (NE4B / NTHR)       // 30 full copy iterations
// remainder copy elements: NE4B - CP_FULL*NTHR = 271,360

__device__ __forceinline__ float dot4(const float4 r, const float4 f) {
    return r.x * f.x + r.y * f.y + r.z * f.z + r.w * f.w;
}

// Thread-private score quad: items u0..u0+3 (u0 = 4q). Each lane reads the
// full 512B row itself (32 x float4) -> 64 rows in flight per wave, no
// cross-lane reduce, coalesced int4 idx load and float4 score store.
__device__ __forceinline__ void score_quad(
        unsigned q,
        const float* __restrict__ l, const float* __restrict__ ab,
        const float* __restrict__ mem_l, const float* __restrict__ mem_ab,
        const int* __restrict__ idx, float* __restrict__ out) {
    const unsigned u0   = 4u * q;
    const unsigned bank = (u0 >= (unsigned)BK_) ? 1u : 0u;
    const unsigned uu   = u0 - bank * (unsigned)BK_;
    const unsigned b    = uu / KP1;             // magic-mul div
    const unsigned k0   = uu - b * KP1;

    const float* mem  = bank ? mem_l : mem_ab;  // out_l uses mem_ab, out_ab uses mem_l
    const float* feat = bank ? ab    : l;

    if (k0 <= (unsigned)(KP1 - 4)) {
        // fast path: all 4 items share (bank, b)
        const int4 i4 = *(const int4*)(idx + uu);
        const float4* r0 = (const float4*)(mem + (size_t)i4.x * D_);
        const float4* r1 = (const float4*)(mem + (size_t)i4.y * D_);
        const float4* r2 = (const float4*)(mem + (size_t)i4.z * D_);
        const float4* r3 = (const float4*)(mem + (size_t)i4.w * D_);
        const float4* fp = (const float4*)(feat + (size_t)b * D_);

        float a0 = 0.f, a1 = 0.f, a2 = 0.f, a3 = 0.f;
        #pragma unroll 4
        for (int j = 0; j < 32; ++j) {
            const float4 f = fp[j];
            a0 += dot4(r0[j], f);
            a1 += dot4(r1[j], f);
            a2 += dot4(r2[j], f);
            a3 += dot4(r3[j], f);
        }
        float4 o;
        o.x = a0 * INV_T; o.y = a1 * INV_T; o.z = a2 * INV_T; o.w = a3 * INV_T;
        *(float4*)(out + u0) = o;
    } else {
        // slow path: quad crosses a b boundary (never a bank boundary: BK_%4==0)
        #pragma unroll
        for (int i = 0; i < 4; ++i) {
            const unsigned u  = u0 + i;
            const unsigned ub = u - bank * (unsigned)BK_;
            const unsigned bi = ub / KP1;
            const float4* rp = (const float4*)(mem + (size_t)idx[ub] * D_);
            const float4* fp = (const float4*)(feat + (size_t)bi * D_);
            float a = 0.f;
            #pragma unroll 4
            for (int j = 0; j < 32; ++j) a += dot4(rp[j], fp[j]);
            out[u] = a * INV_T;
        }
    }
}

// Fused: every thread does its score quad (high-MLP gathers) then its share
// of the streaming bank copy; wave desync overlaps the two traffic types.
__global__ __launch_bounds__(256)
void fused_kernel(const float* __restrict__ l,
                  const float* __restrict__ ab,
                  const float* __restrict__ mem_l,
                  const float* __restrict__ mem_ab,
                  const int* __restrict__ idx,
                  float* __restrict__ out,           // scores [TOT_]
                  float* __restrict__ out_mem_l,
                  float* __restrict__ out_mem_ab) {
    const unsigned tid = blockIdx.x * 256u + threadIdx.x;

    score_quad(tid, l, ab, mem_l, mem_ab, idx, out);
    if (tid < REMQ)
        score_quad((unsigned)NTHR + tid, l, ab, mem_l, mem_ab, idx, out);

    const float4* srcL = (const float4*)mem_l;
    const float4* srcA = (const float4*)mem_ab;
    float4* dstL = (float4*)out_mem_l;
    float4* dstA = (float4*)out_mem_ab;

    #pragma unroll 2
    for (int j = 0; j < CP_FULL; ++j) {
        const size_t e = (size_t)j * NTHR + tid;
        dstL[e] = srcL[e];
        dstA[e] = srcA[e];
    }
    const size_t e = (size_t)CP_FULL * NTHR + tid;
    if (e < (size_t)NE4B) {
        dstL[e] = srcL[e];
        dstA[e] = srcA[e];
    }
}

// EMA + L2-normalize the B updated rows; runs AFTER fused_kernel (stream
// order) so it overwrites the copied rows. Reads ORIGINAL banks from d_in.
__global__ __launch_bounds__(128)
void ema_update_kernel(const float* __restrict__ l,
                       const float* __restrict__ ab,
                       const float* __restrict__ mem_l,
                       const float* __restrict__ mem_ab,
                       const int* __restrict__ y,
                       float* __restrict__ out_mem_l,
                       float* __restrict__ out_mem_ab) {
    const int b    = blockIdx.x;
    const int wave = threadIdx.x >> 6;
    const int lane = threadIdx.x & 63;
    const int yb   = y[b];

    const float* mem  = wave ? mem_ab     : mem_l;
    const float* feat = wave ? ab         : l;
    float*       om   = wave ? out_mem_ab : out_mem_l;

    const float2 m2 = ((const float2*)(mem  + (size_t)yb * D_))[lane];
    const float2 f2 = ((const float2*)(feat + (size_t)b  * D_))[lane];

    float px = m2.x * MOM_ + f2.x * (1.0f - MOM_);
    float py = m2.y * MOM_ + f2.y * (1.0f - MOM_);
    float ss = px * px + py * py;
    #pragma unroll
    for (int m = 32; m >= 1; m >>= 1) ss += __shfl_xor(ss, m);
    const float rn = 1.0f / sqrtf(ss);

    ((float2*)(om + (size_t)yb * D_))[lane] = make_float2(px * rn, py * rn);
}

extern "C" void kernel_launch(void* const* d_in, const int* in_sizes, int n_in,
                              void* d_out, int out_size, void* d_ws, size_t ws_size,
                              hipStream_t stream) {
    const float* l      = (const float*)d_in[0];
    const float* ab     = (const float*)d_in[1];
    const float* mem_l  = (const float*)d_in[2];
    const float* mem_ab = (const float*)d_in[3];
    const int*   y      = (const int*)d_in[4];
    const int*   idx    = (const int*)d_in[5];
    float* out = (float*)d_out;

    float* out_mem_l  = out + (size_t)TOT_;
    float* out_mem_ab = out_mem_l + (size_t)NROW * D_;

    fused_kernel<<<NBLK, 256, 0, stream>>>(l, ab, mem_l, mem_ab, idx,
                                           out, out_mem_l, out_mem_ab);
    ema_update_kernel<<<B_, 128, 0, stream>>>(l, ab, mem_l, mem_ab, y,
                                              out_mem_l, out_mem_ab);
}

// Round 8
// 317.015 us; speedup vs baseline: 3.8312x; 3.8312x over previous
//
#include <hip/hip_runtime.h>
#include <math.h>

#define B_    64
#define KP1   16385                // K+1
#define D_    128
#define N_    500000
#define INV_T (1.0f / 0.07f)
#define MOM_  0.5f

#define NBLK   2048
#define NTHR   (NBLK * 256)        // 524288 threads
#define NGRP   (NBLK * 8)          // 16384 32-lane groups
#define BK_    (B_ * KP1)          // 1048640 items per bank
#define TOT_   (2 * BK_)           // 2097280 score items (flat out index == t)
#define NQUAD  (TOT_ / 4)          // 524320 quads
#define NE4B   (N_ * D_ / 4)       // 16,000,000 float4 per bank
#define BASEQ  32                  // j-steps (score quads per group)
#define REMG   (NQUAD - BASEQ * NGRP)   // 32 leftover quads -> first 32 groups

typedef float vfloat4 __attribute__((ext_vector_type(4)));

__device__ __forceinline__ float dot4(const float4 r, const float4 f) {
    return r.x * f.x + r.y * f.y + r.z * f.z + r.w * f.w;
}

__device__ __forceinline__ void score_quad(
        unsigned t, int glane,
        const float* __restrict__ l, const float* __restrict__ ab,
        const float* __restrict__ mem_l, const float* __restrict__ mem_ab,
        const int* __restrict__ idx, float* __restrict__ out) {
    // items t..t+3 ; flat out index == t ; u = t mod BK_ indexes idx
    const unsigned bank0 = (t >= (unsigned)BK_) ? 1u : 0u;
    const unsigned u0    = t - bank0 * (unsigned)BK_;
    const unsigned b0    = u0 / KP1;             // magic-mul div
    const unsigned k0    = u0 - b0 * KP1;

    if (k0 <= (unsigned)(KP1 - 4)) {
        // fast path: all 4 items share (bank, b); row read is a cooperative
        // 32-lane x 16B = 512B contiguous burst
        const float* mem  = bank0 ? mem_l : mem_ab;
        const float* feat = bank0 ? ab    : l;
        const float4 f = ((const float4*)(feat + (size_t)b0 * D_))[glane];

        const int i0 = idx[u0],     i1 = idx[u0 + 1];
        const int i2 = idx[u0 + 2], i3 = idx[u0 + 3];
        const float4 r0 = ((const float4*)(mem + (size_t)i0 * D_))[glane];
        const float4 r1 = ((const float4*)(mem + (size_t)i1 * D_))[glane];
        const float4 r2 = ((const float4*)(mem + (size_t)i2 * D_))[glane];
        const float4 r3 = ((const float4*)(mem + (size_t)i3 * D_))[glane];

        float v0 = dot4(r0, f), v1 = dot4(r1, f);
        float v2 = dot4(r2, f), v3 = dot4(r3, f);
        #pragma unroll
        for (int m = 16; m >= 1; m >>= 1) {
            v0 += __shfl_xor(v0, m);
            v1 += __shfl_xor(v1, m);
            v2 += __shfl_xor(v2, m);
            v3 += __shfl_xor(v3, m);
        }
        float vv = glane == 1 ? v1 : glane == 2 ? v2 : glane == 3 ? v3 : v0;
        if (glane < 4)
            __builtin_nontemporal_store(vv * INV_T, out + t + glane);
    } else {
        // slow path: quad crosses a b (or bank) boundary
        #pragma unroll
        for (int i = 0; i < 4; ++i) {
            const unsigned ti = t + i;
            const unsigned bk = (ti >= (unsigned)BK_) ? 1u : 0u;
            const unsigned u  = ti - bk * (unsigned)BK_;
            const unsigned b  = u / KP1;
            const float* mem  = bk ? mem_l : mem_ab;
            const float* feat = bk ? ab    : l;
            const float4 f = ((const float4*)(feat + (size_t)b * D_))[glane];
            const int ri = idx[u];
            const float4 r = ((const float4*)(mem + (size_t)ri * D_))[glane];
            float v = dot4(r, f);
            #pragma unroll
            for (int m = 16; m >= 1; m >>= 1) v += __shfl_xor(v, m);
            if (glane == 0)
                __builtin_nontemporal_store(v * INV_T, out + ti);
        }
    }
}

__device__ __forceinline__ void copy_iter(const vfloat4* __restrict__ src,
                                          vfloat4* __restrict__ dst,
                                          unsigned c, unsigned tid) {
    const size_t e = (size_t)c * NTHR + tid;
    if (e < (size_t)NE4B) {
        const vfloat4 v = src[e];
        __builtin_nontemporal_store(v, dst + e);  // don't pollute L3 with writes
    }
}

// Bank-phased uniform-mixed kernel: flat score order does bank-ab items
// (out_l) in j=0..15 and bank-l items (out_ab) in j=16..31. The streaming
// copy is phased to match: phase A streams mem_ab only (2 copy iters / j),
// phase B streams mem_l. One 256MB bank at a time competes for the 256MB L3,
// and NT stores keep writes from evicting it.
__global__ __launch_bounds__(256)
void fused_kernel(const float* __restrict__ l,
                  const float* __restrict__ ab,
                  const float* __restrict__ mem_l,
                  const float* __restrict__ mem_ab,
                  const int* __restrict__ idx,
                  float* __restrict__ out,          // scores [TOT_]
                  float* __restrict__ out_mem_l,
                  float* __restrict__ out_mem_ab) {
    const unsigned tid   = blockIdx.x * 256u + threadIdx.x;
    const int      glane = threadIdx.x & 31;
    const unsigned g     = (blockIdx.x << 3) + (threadIdx.x >> 5);

    const vfloat4* srcL = (const vfloat4*)mem_l;
    const vfloat4* srcA = (const vfloat4*)mem_ab;
    vfloat4* dstL = (vfloat4*)out_mem_l;
    vfloat4* dstA = (vfloat4*)out_mem_ab;

    // Phase A: copy mem_ab while scoring bank0 (= gathers from mem_ab)
    #pragma unroll 2
    for (int j = 0; j < BASEQ / 2; ++j) {
        copy_iter(srcA, dstA, 2 * j,     tid);
        copy_iter(srcA, dstA, 2 * j + 1, tid);
        score_quad(4u * (g + (unsigned)j * NGRP), glane,
                   l, ab, mem_l, mem_ab, idx, out);
    }
    // Phase B: copy mem_l while scoring bank1 (= gathers from mem_l)
    #pragma unroll 2
    for (int j = BASEQ / 2; j < BASEQ; ++j) {
        const int c = j - BASEQ / 2;
        copy_iter(srcL, dstL, 2 * c,     tid);
        copy_iter(srcL, dstL, 2 * c + 1, tid);
        score_quad(4u * (g + (unsigned)j * NGRP), glane,
                   l, ab, mem_l, mem_ab, idx, out);
    }
    if (g < REMG)
        score_quad(4u * ((unsigned)BASEQ * NGRP + g), glane,
                   l, ab, mem_l, mem_ab, idx, out);
}

// EMA + L2-normalize the B updated rows; runs AFTER fused_kernel (stream
// order) so it overwrites the copied rows. Reads ORIGINAL banks from d_in.
__global__ __launch_bounds__(128)
void ema_update_kernel(const float* __restrict__ l,
                       const float* __restrict__ ab,
                       const float* __restrict__ mem_l,
                       const float* __restrict__ mem_ab,
                       const int* __restrict__ y,
                       float* __restrict__ out_mem_l,
                       float* __restrict__ out_mem_ab) {
    const int b    = blockIdx.x;
    const int wave = threadIdx.x >> 6;
    const int lane = threadIdx.x & 63;
    const int yb   = y[b];

    const float* mem  = wave ? mem_ab     : mem_l;
    const float* feat = wave ? ab         : l;
    float*       om   = wave ? out_mem_ab : out_mem_l;

    const float2 m2 = ((const float2*)(mem  + (size_t)yb * D_))[lane];
    const float2 f2 = ((const float2*)(feat + (size_t)b  * D_))[lane];

    float px = m2.x * MOM_ + f2.x * (1.0f - MOM_);
    float py = m2.y * MOM_ + f2.y * (1.0f - MOM_);
    float ss = px * px + py * py;
    #pragma unroll
    for (int m = 32; m >= 1; m >>= 1) ss += __shfl_xor(ss, m);
    const float rn = 1.0f / sqrtf(ss);

    ((float2*)(om + (size_t)yb * D_))[lane] = make_float2(px * rn, py * rn);
}

extern "C" void kernel_launch(void* const* d_in, const int* in_sizes, int n_in,
                              void* d_out, int out_size, void* d_ws, size_t ws_size,
                              hipStream_t stream) {
    const float* l      = (const float*)d_in[0];
    const float* ab     = (const float*)d_in[1];
    const float* mem_l  = (const float*)d_in[2];
    const float* mem_ab = (const float*)d_in[3];
    const int*   y      = (const int*)d_in[4];
    const int*   idx    = (const int*)d_in[5];
    float* out = (float*)d_out;

    float* out_mem_l  = out + (size_t)TOT_;
    float* out_mem_ab = out_mem_l + (size_t)N_ * D_;

    fused_kernel<<<NBLK, 256, 0, stream>>>(l, ab, mem_l, mem_ab, idx,
                                           out, out_mem_l, out_mem_ab);
    ema_update_kernel<<<B_, 128, 0, stream>>>(l, ab, mem_l, mem_ab, y,
                                              out_mem_l, out_mem_ab);
}